// Round 1
// baseline (284.981 us; speedup 1.0000x reference)
//
#include <hip/hip_runtime.h>
#include <hip/hip_bf16.h>
#include <stdint.h>

// ESPNET MultiHeadedAttention: T=2048 B=2 F=1024 H=16 DK=64
// Pipeline: cvt(fp32->bf16, [T,B,F]->[B,T,F]) -> 3x proj GEMM (bf16 MFMA)
//           -> flash attention (bf16 MFMA, fp32 online softmax) -> out GEMM (fp32 out)

typedef __bf16 bf16_t;
typedef __bf16 bf16x8 __attribute__((ext_vector_type(8)));
typedef float f32x4 __attribute__((ext_vector_type(4)));

typedef const __attribute__((address_space(1))) void* gas_ptr;
typedef __attribute__((address_space(3))) void* las_ptr;

__device__ __forceinline__ void gload16(const void* g, void* lds) {
    // async global->LDS, 16B per lane; LDS dest = wave-uniform base + lane*16
    __builtin_amdgcn_global_load_lds((gas_ptr)g, (las_ptr)lds, 16, 0, 0);
}

// ---------------- mask canonicalization (int32 vs byte-bool hedge) ----------
__global__ __launch_bounds__(256) void prep_mask_kernel(const unsigned char* __restrict__ raw,
                                                        int* __restrict__ canon) {
    __shared__ int s_isbyte;
    int tid = threadIdx.x;
    if (tid == 0) s_isbyte = 0;
    __syncthreads();
    int any = 0;
    for (int i = tid; i < 4096; i += 256)
        if ((i & 3) && raw[i]) any = 1;           // nonzero off-aligned byte => byte layout
    if (any) atomicOr(&s_isbyte, 1);
    __syncthreads();
    if (s_isbyte) {
        for (int i = tid; i < 4096; i += 256) canon[i] = (int)raw[i];
    } else {
        const int* ri = (const int*)raw;
        for (int i = tid; i < 4096; i += 256) canon[i] = ri[i];
    }
}

// ---------------- fp32 [T,B,F] -> bf16 [B,T,F] ------------------------------
__global__ __launch_bounds__(256) void cvt_x_kernel(const float* __restrict__ src,
                                                    bf16_t* __restrict__ dst) {
    int idx = blockIdx.x * 256 + threadIdx.x;   // one thread = 8 elements
    int e0 = idx * 8;
    int t = e0 >> 11;          // / (B*F = 2048)
    int r = e0 & 2047;
    int b = r >> 10;
    int f = r & 1023;
    const float4* s = (const float4*)(src + e0);
    float4 a = s[0], c = s[1];
    bf16x8 o;
    o[0] = (bf16_t)a.x; o[1] = (bf16_t)a.y; o[2] = (bf16_t)a.z; o[3] = (bf16_t)a.w;
    o[4] = (bf16_t)c.x; o[5] = (bf16_t)c.y; o[6] = (bf16_t)c.z; o[7] = (bf16_t)c.w;
    *(bf16x8*)(dst + ((size_t)b * 2048 + t) * 1024 + f) = o;
}

// ---------------- fp32 -> bf16 linear (weights) -----------------------------
__global__ __launch_bounds__(256) void cvt_lin_kernel(const float* __restrict__ src,
                                                      bf16_t* __restrict__ dst) {
    int idx = blockIdx.x * 256 + threadIdx.x;
    int e0 = idx * 8;
    const float4* s = (const float4*)(src + e0);
    float4 a = s[0], c = s[1];
    bf16x8 o;
    o[0] = (bf16_t)a.x; o[1] = (bf16_t)a.y; o[2] = (bf16_t)a.z; o[3] = (bf16_t)a.w;
    o[4] = (bf16_t)c.x; o[5] = (bf16_t)c.y; o[6] = (bf16_t)c.z; o[7] = (bf16_t)c.w;
    *(bf16x8*)(dst + e0) = o;
}

// ---------------- GEMM: C = A[M x 1024] * Bw[1024 x 1024]^T + bias ----------
// Bw stored [N][K] row-major (i.e. torch Linear weight), both operands K-contiguous.
// mode 0: out bf16 scattered to [B,H,T,DK]  (QKV projections)
// mode 1: out fp32 at [T,B,F]               (output projection)
__global__ __launch_bounds__(256) void gemm_kernel(const bf16_t* __restrict__ A,
                                                   const bf16_t* __restrict__ Bw,
                                                   const float* __restrict__ bias,
                                                   bf16_t* __restrict__ outb,
                                                   float* __restrict__ outf,
                                                   int mode) {
    __shared__ __align__(16) bf16_t Asm[128 * 32];
    __shared__ __align__(16) bf16_t Bsm[128 * 32];
    const int tid = threadIdx.x;
    const int wave = tid >> 6, lane = tid & 63;
    const int g = lane >> 4, lr = lane & 15;
    const int m0 = blockIdx.y * 128, n0 = blockIdx.x * 128;
    const int wm = (wave >> 1) * 64, wn = (wave & 1) * 64;
    const int srow = wave * 32 + (lane >> 2);   // + c*16
    const int scol = (lane & 3) * 8;

    f32x4 acc[4][4] = {};

    for (int k0 = 0; k0 < 1024; k0 += 32) {
        __syncthreads();   // previous iteration's LDS reads done
        gload16(A  + (size_t)(m0 + srow) * 1024 + k0 + scol,      (char*)Asm + wave * 2048);
        gload16(A  + (size_t)(m0 + srow + 16) * 1024 + k0 + scol, (char*)Asm + wave * 2048 + 1024);
        gload16(Bw + (size_t)(n0 + srow) * 1024 + k0 + scol,      (char*)Bsm + wave * 2048);
        gload16(Bw + (size_t)(n0 + srow + 16) * 1024 + k0 + scol, (char*)Bsm + wave * 2048 + 1024);
        __syncthreads();   // staging visible (compiler drains vmcnt before barrier)

        bf16x8 af[4], bfr[4];
        #pragma unroll
        for (int mi = 0; mi < 4; ++mi)
            af[mi] = *(const bf16x8*)(Asm + (wm + mi * 16 + lr) * 32 + g * 8);
        #pragma unroll
        for (int ni = 0; ni < 4; ++ni)
            bfr[ni] = *(const bf16x8*)(Bsm + (wn + ni * 16 + lr) * 32 + g * 8);
        #pragma unroll
        for (int mi = 0; mi < 4; ++mi)
            #pragma unroll
            for (int ni = 0; ni < 4; ++ni)
                acc[mi][ni] = __builtin_amdgcn_mfma_f32_16x16x32_bf16(af[mi], bfr[ni], acc[mi][ni], 0, 0, 0);
    }

    #pragma unroll
    for (int mi = 0; mi < 4; ++mi) {
        #pragma unroll
        for (int ni = 0; ni < 4; ++ni) {
            int n = n0 + wn + ni * 16 + lr;
            float bs = bias[n];
            #pragma unroll
            for (int i = 0; i < 4; ++i) {
                int m = m0 + wm + mi * 16 + 4 * g + i;   // D row = 4*(lane>>4)+i, col = lane&15
                float v = acc[mi][ni][i] + bs;
                int b = m >> 11, t = m & 2047;
                if (mode == 0) {
                    int hh = n >> 6, dk = n & 63;
                    outb[((size_t)(b * 16 + hh) * 2048 + t) * 64 + dk] = (bf16_t)v;
                } else {
                    outf[(size_t)t * 2048 + b * 1024 + n] = v;
                }
            }
        }
    }
}

// ---------------- flash attention ------------------------------------------
// grid: (T/64, B*H); block 256 = 4 waves; wave owns a 16-q-row strip.
__global__ __launch_bounds__(256) void attn_kernel(const bf16_t* __restrict__ qh,
                                                   const bf16_t* __restrict__ kh,
                                                   const bf16_t* __restrict__ vh,
                                                   const int* __restrict__ kpm,
                                                   bf16_t* __restrict__ ctx) {
    __shared__ __align__(16) bf16_t Qs[64 * 64];
    __shared__ __align__(16) bf16_t Ks[64 * 64];
    __shared__ __align__(16) bf16_t Vt[64 * 88];   // transposed V [dk][key], stride 88
    __shared__ __align__(16) bf16_t Ps[64 * 64];

    const int tid = threadIdx.x;
    const int wave = tid >> 6, lane = tid & 63;
    const int g = lane >> 4, lr = lane & 15;
    const int bh = blockIdx.y;
    const int b = bh >> 4, h = bh & 15;
    const int q0 = blockIdx.x * 64;
    const bf16_t* Qg = qh + ((size_t)bh * 2048 + q0) * 64;
    const bf16_t* Kg = kh + (size_t)bh * 2048 * 64;
    const bf16_t* Vg = vh + (size_t)bh * 2048 * 64;
    const int* maskb = kpm + b * 2048;

    // stage Q tile (contiguous 8KB, layout == global layout)
    gload16((const char*)Qg + wave * 2048 + lane * 16,        (char*)Qs + wave * 2048);
    gload16((const char*)Qg + wave * 2048 + 1024 + lane * 16, (char*)Qs + wave * 2048 + 1024);
    __syncthreads();

    const int wq0 = wave * 16;
    bf16x8 qf0 = *(const bf16x8*)(Qs + (wq0 + lr) * 64 + g * 8);
    bf16x8 qf1 = *(const bf16x8*)(Qs + (wq0 + lr) * 64 + 32 + g * 8);

    f32x4 cacc[4] = {};
    float mrun[4] = {-1e30f, -1e30f, -1e30f, -1e30f};
    float lrun[4] = {0.f, 0.f, 0.f, 0.f};

    for (int kt = 0; kt < 32; ++kt) {
        __syncthreads();   // previous tile's LDS reads done
        const char* Kt = (const char*)(Kg + kt * 4096);
        gload16(Kt + wave * 2048 + lane * 16,        (char*)Ks + wave * 2048);
        gload16(Kt + wave * 2048 + 1024 + lane * 16, (char*)Ks + wave * 2048 + 1024);
        const bf16_t* Vtile = Vg + kt * 4096;
        #pragma unroll
        for (int c = 0; c < 2; ++c) {
            int d0 = (wave + c * 4) * 8;
            bf16x8 v = *(const bf16x8*)(Vtile + lane * 64 + d0);
            #pragma unroll
            for (int j = 0; j < 8; ++j)
                Vt[(d0 + j) * 88 + lane] = v[j];    // key==lane -> conflict-free-ish writes
        }
        __syncthreads();   // K + Vt visible

        // S = Q K^T  (A rows = q, B cols = keys); slot-k consistent on both operands
        f32x4 s[4] = {};
        #pragma unroll
        for (int st = 0; st < 4; ++st) {
            bf16x8 kf0 = *(const bf16x8*)(Ks + (st * 16 + lr) * 64 + g * 8);
            bf16x8 kf1 = *(const bf16x8*)(Ks + (st * 16 + lr) * 64 + 32 + g * 8);
            s[st] = __builtin_amdgcn_mfma_f32_16x16x32_bf16(qf0, kf0, s[st], 0, 0, 0);
            s[st] = __builtin_amdgcn_mfma_f32_16x16x32_bf16(qf1, kf1, s[st], 0, 0, 0);
        }
        // scale + key padding mask
        #pragma unroll
        for (int st = 0; st < 4; ++st) {
            int key = kt * 64 + st * 16 + lr;
            bool mk = maskb[key] != 0;
            #pragma unroll
            for (int i = 0; i < 4; ++i)
                s[st][i] = mk ? -1e30f : s[st][i] * 0.125f;
        }
        // row max (rows = 4g+i live across the 16-lane group)
        float mt[4];
        #pragma unroll
        for (int i = 0; i < 4; ++i)
            mt[i] = fmaxf(fmaxf(s[0][i], s[1][i]), fmaxf(s[2][i], s[3][i]));
        #pragma unroll
        for (int off = 1; off < 16; off <<= 1)
            #pragma unroll
            for (int i = 0; i < 4; ++i)
                mt[i] = fmaxf(mt[i], __shfl_xor(mt[i], off));
        float alpha[4];
        #pragma unroll
        for (int i = 0; i < 4; ++i) {
            float mn = fmaxf(mrun[i], mt[i]);
            alpha[i] = __expf(mrun[i] - mn);
            mrun[i] = mn;
        }
        float rs[4] = {0.f, 0.f, 0.f, 0.f};
        #pragma unroll
        for (int st = 0; st < 4; ++st)
            #pragma unroll
            for (int i = 0; i < 4; ++i) {
                float p = __expf(s[st][i] - mrun[i]);   // masked: exp(-1e30) = 0
                s[st][i] = p;
                rs[i] += p;
            }
        #pragma unroll
        for (int off = 1; off < 16; off <<= 1)
            #pragma unroll
            for (int i = 0; i < 4; ++i)
                rs[i] += __shfl_xor(rs[i], off);
        #pragma unroll
        for (int i = 0; i < 4; ++i)
            lrun[i] = lrun[i] * alpha[i] + rs[i];
        #pragma unroll
        for (int ni = 0; ni < 4; ++ni)
            #pragma unroll
            for (int i = 0; i < 4; ++i)
                cacc[ni][i] *= alpha[i];
        // P -> LDS (own 16-row strip only; same-wave ds order, no barrier needed)
        #pragma unroll
        for (int st = 0; st < 4; ++st)
            #pragma unroll
            for (int i = 0; i < 4; ++i)
                Ps[(wq0 + 4 * g + i) * 64 + st * 16 + lr] = (bf16_t)s[st][i];
        // PV: A = P[16 x 64], B = V[key][dk] via transposed Vt
        #pragma unroll
        for (int kk = 0; kk < 2; ++kk) {
            bf16x8 pf = *(const bf16x8*)(Ps + (wq0 + lr) * 64 + kk * 32 + g * 8);
            #pragma unroll
            for (int ni = 0; ni < 4; ++ni) {
                bf16x8 vf = *(const bf16x8*)(Vt + (ni * 16 + lr) * 88 + kk * 32 + g * 8);
                cacc[ni] = __builtin_amdgcn_mfma_f32_16x16x32_bf16(pf, vf, cacc[ni], 0, 0, 0);
            }
        }
    }

    #pragma unroll
    for (int ni = 0; ni < 4; ++ni) {
        int dk = ni * 16 + lr;
        #pragma unroll
        for (int i = 0; i < 4; ++i) {
            int trow = q0 + wq0 + 4 * g + i;
            float v = cacc[ni][i] / lrun[i];
            ctx[((size_t)b * 2048 + trow) * 1024 + h * 64 + dk] = (bf16_t)v;
        }
    }
}

// ---------------- launch ----------------------------------------------------
extern "C" void kernel_launch(void* const* d_in, const int* in_sizes, int n_in,
                              void* d_out, int out_size, void* d_ws, size_t ws_size,
                              hipStream_t stream) {
    const float* query = (const float*)d_in[0];
    const float* key_  = (const float*)d_in[1];
    const float* value = (const float*)d_in[2];
    const unsigned char* kpm_raw = (const unsigned char*)d_in[3];
    const float* Wq = (const float*)d_in[4];
    const float* bq = (const float*)d_in[5];
    const float* Wk = (const float*)d_in[6];
    const float* bk = (const float*)d_in[7];
    const float* Wv = (const float*)d_in[8];
    const float* bv = (const float*)d_in[9];
    const float* Wo = (const float*)d_in[10];
    const float* bo = (const float*)d_in[11];
    float* out = (float*)d_out;

    char* ws = (char*)d_ws;
    size_t off = 0;
    auto alloc = [&](size_t bytes) {
        char* p = ws + off;
        off += (bytes + 255) & ~(size_t)255;
        return p;
    };
    const size_t SZ_X = (size_t)4096 * 1024 * sizeof(bf16_t);  // 8 MB
    const size_t SZ_W = (size_t)1024 * 1024 * sizeof(bf16_t);  // 2 MB
    bf16_t* xq  = (bf16_t*)alloc(SZ_X);
    bf16_t* xk  = (bf16_t*)alloc(SZ_X);
    bf16_t* xv  = (bf16_t*)alloc(SZ_X);
    bf16_t* wqb = (bf16_t*)alloc(SZ_W);
    bf16_t* wkb = (bf16_t*)alloc(SZ_W);
    bf16_t* wvb = (bf16_t*)alloc(SZ_W);
    bf16_t* wob = (bf16_t*)alloc(SZ_W);
    bf16_t* qhB = (bf16_t*)alloc(SZ_X);
    bf16_t* khB = (bf16_t*)alloc(SZ_X);
    bf16_t* vhB = (bf16_t*)alloc(SZ_X);
    bf16_t* ctxB = (bf16_t*)alloc(SZ_X);
    int* maskC = (int*)alloc(4096 * sizeof(int));

    prep_mask_kernel<<<1, 256, 0, stream>>>(kpm_raw, maskC);
    cvt_x_kernel<<<2048, 256, 0, stream>>>(query, xq);
    cvt_x_kernel<<<2048, 256, 0, stream>>>(key_,  xk);
    cvt_x_kernel<<<2048, 256, 0, stream>>>(value, xv);
    cvt_lin_kernel<<<512, 256, 0, stream>>>(Wq, wqb);
    cvt_lin_kernel<<<512, 256, 0, stream>>>(Wk, wkb);
    cvt_lin_kernel<<<512, 256, 0, stream>>>(Wv, wvb);
    cvt_lin_kernel<<<512, 256, 0, stream>>>(Wo, wob);

    dim3 gproj(8, 32);   // N/128 x M/128
    gemm_kernel<<<gproj, 256, 0, stream>>>(xq, wqb, bq, qhB, nullptr, 0);
    gemm_kernel<<<gproj, 256, 0, stream>>>(xk, wkb, bk, khB, nullptr, 0);
    gemm_kernel<<<gproj, 256, 0, stream>>>(xv, wvb, bv, vhB, nullptr, 0);

    dim3 gattn(32, 32);  // T/64 x B*H
    attn_kernel<<<gattn, 256, 0, stream>>>(qhB, khB, vhB, maskC, ctxB);

    gemm_kernel<<<gproj, 256, 0, stream>>>(ctxB, wob, bo, nullptr, out, 1);
}

// Round 2
// 275.743 us; speedup vs baseline: 1.0335x; 1.0335x over previous
//
#include <hip/hip_runtime.h>
#include <hip/hip_bf16.h>
#include <stdint.h>

// ESPNET MultiHeadedAttention: T=2048 B=2 F=1024 H=16 DK=64
// cvt(fp32->bf16) -> 3x proj GEMM (bf16 MFMA) -> flash attn (swizzled LDS,
// K/V prefetch pipeline) -> out GEMM (fp32 out)

typedef __bf16 bf16_t;
typedef __bf16 bf16x8 __attribute__((ext_vector_type(8)));
typedef float f32x4 __attribute__((ext_vector_type(4)));

typedef const __attribute__((address_space(1))) void* gas_ptr;
typedef __attribute__((address_space(3))) void* las_ptr;

__device__ __forceinline__ void gload16(const void* g, void* lds) {
    // async global->LDS, 16B/lane; LDS dest = wave-uniform base + lane*16
    __builtin_amdgcn_global_load_lds((gas_ptr)g, (las_ptr)lds, 16, 0, 0);
}

// XOR swizzle for 128-B-row tiles: involution, preserves 16B blocks, stays in-row
__device__ __forceinline__ int swz(int o) { return o ^ (((o >> 7) & 7) << 4); }

#if __has_builtin(__builtin_amdgcn_exp2f)
#define EXP2F(x) __builtin_amdgcn_exp2f(x)
#else
#define EXP2F(x) exp2f(x)
#endif

// ---------------- mask -> per-tile 64-bit masks (int32 vs byte-bool hedge) --
__global__ __launch_bounds__(64) void prep_mask_kernel(const unsigned char* __restrict__ raw,
                                                       unsigned long long* __restrict__ mbits) {
    __shared__ int s_isbyte;
    int lane = threadIdx.x;
    if (lane == 0) s_isbyte = 0;
    __syncthreads();
    int any = 0;
    for (int i = lane; i < 4096; i += 64)
        if ((i & 3) && raw[i]) any = 1;      // nonzero off-aligned byte => byte layout
    if (any) atomicOr(&s_isbyte, 1);
    __syncthreads();
    int b = lane >> 5, kt = lane & 31;       // 64 threads: one (b, key-tile) each
    unsigned long long bits = 0;
    if (s_isbyte) {
        for (int j = 0; j < 64; ++j)
            if (raw[b * 2048 + kt * 64 + j]) bits |= 1ull << j;
    } else {
        const int* ri = (const int*)raw;
        for (int j = 0; j < 64; ++j)
            if (ri[b * 2048 + kt * 64 + j]) bits |= 1ull << j;
    }
    mbits[lane] = bits;
}

// ---------------- fp32 [T,B,F] -> bf16 [B,T,F], all 3 tensors --------------
__global__ __launch_bounds__(256) void cvt_x3_kernel(const float* __restrict__ q,
                                                     const float* __restrict__ k,
                                                     const float* __restrict__ v,
                                                     bf16_t* __restrict__ dst) {
    int idx = blockIdx.x * 256 + threadIdx.x;
    int which = idx >> 19;                   // 524288 threads per tensor
    int loc = idx & 524287;
    const float* src = which == 0 ? q : which == 1 ? k : v;
    int e0 = loc * 8;
    int t = e0 >> 11, r = e0 & 2047, b = r >> 10, f = r & 1023;
    const float4* s = (const float4*)(src + e0);
    float4 a = s[0], c = s[1];
    bf16x8 o;
    o[0] = (bf16_t)a.x; o[1] = (bf16_t)a.y; o[2] = (bf16_t)a.z; o[3] = (bf16_t)a.w;
    o[4] = (bf16_t)c.x; o[5] = (bf16_t)c.y; o[6] = (bf16_t)c.z; o[7] = (bf16_t)c.w;
    *(bf16x8*)(dst + (size_t)which * 4194304 + ((size_t)b * 2048 + t) * 1024 + f) = o;
}

// ---------------- fp32 -> bf16, all 4 weight matrices (contiguous dst) ------
__global__ __launch_bounds__(256) void cvt_w4_kernel(const float* __restrict__ wq,
                                                     const float* __restrict__ wk,
                                                     const float* __restrict__ wv,
                                                     const float* __restrict__ wo,
                                                     bf16_t* __restrict__ dst) {
    int idx = blockIdx.x * 256 + threadIdx.x;
    int which = idx >> 17;                   // 131072 threads per matrix
    int loc = idx & 131071;
    const float* src = which == 0 ? wq : which == 1 ? wk : which == 2 ? wv : wo;
    int e0 = loc * 8;
    const float4* s = (const float4*)(src + e0);
    float4 a = s[0], c = s[1];
    bf16x8 o;
    o[0] = (bf16_t)a.x; o[1] = (bf16_t)a.y; o[2] = (bf16_t)a.z; o[3] = (bf16_t)a.w;
    o[4] = (bf16_t)c.x; o[5] = (bf16_t)c.y; o[6] = (bf16_t)c.z; o[7] = (bf16_t)c.w;
    *(bf16x8*)(dst + (size_t)which * 1048576 + e0) = o;
}

// ---------------- GEMM: C = A[M x 1024] * Bw[1024 x 1024]^T + bias ----------
// mode 0: out bf16 scattered to [B,H,T,DK]; mode 1: out fp32 at [T,B,F]
__global__ __launch_bounds__(256) void gemm_kernel(const bf16_t* __restrict__ A,
                                                   const bf16_t* __restrict__ Bw,
                                                   const float* __restrict__ bias,
                                                   bf16_t* __restrict__ outb,
                                                   float* __restrict__ outf,
                                                   int mode) {
    __shared__ __align__(16) bf16_t Asm[128 * 32];
    __shared__ __align__(16) bf16_t Bsm[128 * 32];
    const int tid = threadIdx.x;
    const int wave = tid >> 6, lane = tid & 63;
    const int g = lane >> 4, lr = lane & 15;
    const int m0 = blockIdx.y * 128, n0 = blockIdx.x * 128;
    const int wm = (wave >> 1) * 64, wn = (wave & 1) * 64;
    const int srow = wave * 32 + (lane >> 2);
    const int scol = (lane & 3) * 8;

    f32x4 acc[4][4] = {};

    for (int k0 = 0; k0 < 1024; k0 += 32) {
        __syncthreads();
        gload16(A  + (size_t)(m0 + srow) * 1024 + k0 + scol,      (char*)Asm + wave * 2048);
        gload16(A  + (size_t)(m0 + srow + 16) * 1024 + k0 + scol, (char*)Asm + wave * 2048 + 1024);
        gload16(Bw + (size_t)(n0 + srow) * 1024 + k0 + scol,      (char*)Bsm + wave * 2048);
        gload16(Bw + (size_t)(n0 + srow + 16) * 1024 + k0 + scol, (char*)Bsm + wave * 2048 + 1024);
        __syncthreads();

        bf16x8 af[4], bfr[4];
        #pragma unroll
        for (int mi = 0; mi < 4; ++mi)
            af[mi] = *(const bf16x8*)(Asm + (wm + mi * 16 + lr) * 32 + g * 8);
        #pragma unroll
        for (int ni = 0; ni < 4; ++ni)
            bfr[ni] = *(const bf16x8*)(Bsm + (wn + ni * 16 + lr) * 32 + g * 8);
        #pragma unroll
        for (int mi = 0; mi < 4; ++mi)
            #pragma unroll
            for (int ni = 0; ni < 4; ++ni)
                acc[mi][ni] = __builtin_amdgcn_mfma_f32_16x16x32_bf16(af[mi], bfr[ni], acc[mi][ni], 0, 0, 0);
    }

    #pragma unroll
    for (int mi = 0; mi < 4; ++mi) {
        #pragma unroll
        for (int ni = 0; ni < 4; ++ni) {
            int n = n0 + wn + ni * 16 + lr;
            float bs = bias[n];
            #pragma unroll
            for (int i = 0; i < 4; ++i) {
                int m = m0 + wm + mi * 16 + 4 * g + i;
                float v = acc[mi][ni][i] + bs;
                int b = m >> 11, t = m & 2047;
                if (mode == 0) {
                    int hh = n >> 6, dk = n & 63;
                    outb[((size_t)(b * 16 + hh) * 2048 + t) * 64 + dk] = (bf16_t)v;
                } else {
                    outf[(size_t)t * 2048 + b * 1024 + n] = v;
                }
            }
        }
    }
}

// ---------------- flash attention (swizzled LDS + K/V prefetch) -------------
// grid (T/64, B*H); 4 waves; wave owns 16 q-rows. LDS = 8K(QP) + 16K(K dbuf) + 8K(Vt) = 32KB
__global__ __launch_bounds__(256) void attn_kernel(const bf16_t* __restrict__ qh,
                                                   const bf16_t* __restrict__ kh,
                                                   const bf16_t* __restrict__ vh,
                                                   const unsigned long long* __restrict__ mbits,
                                                   bf16_t* __restrict__ ctx) {
    __shared__ __align__(16) bf16_t QPs[64 * 64];      // Q tile, then P tile (per-wave strips)
    __shared__ __align__(16) bf16_t Ks[2][64 * 64];    // double-buffered K
    __shared__ __align__(16) bf16_t Vt[64 * 64];       // V^T [dk][key], swizzled

    const int tid = threadIdx.x;
    const int wave = tid >> 6, lane = tid & 63;
    const int g = lane >> 4, lr = lane & 15;
    const int bh = blockIdx.y;
    const int b = bh >> 4, h = bh & 15;
    const int q0 = blockIdx.x * 64;
    const bf16_t* Qg = qh + ((size_t)bh * 2048 + q0) * 64;
    const bf16_t* Kg = kh + (size_t)bh * 2048 * 64;
    const bf16_t* Vg = vh + (size_t)bh * 2048 * 64;
    const unsigned long long* mbp = mbits + b * 32;

    const int dstw = wave * 2048;            // wave's 2KB staging chunk (byte offset)
    const int dl = dstw + lane * 16;

    // stage Q: pre-swizzled global source, linear LDS dest (rule 21)
    gload16((const char*)Qg + swz(dl),        (char*)QPs + dstw);
    gload16((const char*)Qg + swz(dl + 1024), (char*)QPs + dstw + 1024);
    __syncthreads();

    const int wq0 = wave * 16;
    bf16x8 qf0 = *(const bf16x8*)((const char*)QPs + swz((wq0 + lr) * 128 + g * 16));
    bf16x8 qf1 = *(const bf16x8*)((const char*)QPs + swz((wq0 + lr) * 128 + 64 + g * 16));

    // prologue prefetch: K0 -> Ks[0], V0 -> regs
    gload16((const char*)Kg + swz(dl),        (char*)Ks[0] + dstw);
    gload16((const char*)Kg + swz(dl + 1024), (char*)Ks[0] + dstw + 1024);
    bf16x8 v0 = *(const bf16x8*)(Vg + lane * 64 + wave * 8);
    bf16x8 v1 = *(const bf16x8*)(Vg + lane * 64 + (wave + 4) * 8);

    f32x4 cacc[4] = {};
    float mrun[4] = {-1e30f, -1e30f, -1e30f, -1e30f};
    float lrun[4] = {0.f, 0.f, 0.f, 0.f};
    const float SCALE = 0.125f * 1.44269504f;   // 1/sqrt(64) * log2(e)

    for (int kt = 0; kt < 32; ++kt) {
        const int cur = kt & 1;
        __syncthreads();   // K[kt] staged, V[kt] in regs; prev Vt/Ks reads done
        const unsigned long long mb = mbp[kt];

        // write V^T tile (swizzled [dk][key]); dk rows owned per (wave, half)
        #pragma unroll
        for (int j = 0; j < 8; ++j) {
            *(bf16_t*)((char*)Vt + swz((wave * 8 + j) * 128 + lane * 2))       = v0[j];
            *(bf16_t*)((char*)Vt + swz(((wave + 4) * 8 + j) * 128 + lane * 2)) = v1[j];
        }
        __syncthreads();   // Vt visible (lgkm-only drain: cheap)

        // prefetch next K (async -> other buffer) and V (-> regs); in flight across compute
        const int nx = (kt < 31) ? kt + 1 : 31;
        const char* Kn = (const char*)(Kg + nx * 4096);
        gload16(Kn + swz(dl),        (char*)Ks[cur ^ 1] + dstw);
        gload16(Kn + swz(dl + 1024), (char*)Ks[cur ^ 1] + dstw + 1024);
        const bf16_t* Vn = Vg + nx * 4096;
        v0 = *(const bf16x8*)(Vn + lane * 64 + wave * 8);
        v1 = *(const bf16x8*)(Vn + lane * 64 + (wave + 4) * 8);

        // S = Q K^T
        const char* Kc = (const char*)Ks[cur];
        f32x4 s[4];
        __builtin_amdgcn_s_setprio(1);
        #pragma unroll
        for (int st = 0; st < 4; ++st) {
            bf16x8 kf0 = *(const bf16x8*)(Kc + swz((st * 16 + lr) * 128 + g * 16));
            bf16x8 kf1 = *(const bf16x8*)(Kc + swz((st * 16 + lr) * 128 + 64 + g * 16));
            f32x4 z = {};
            z = __builtin_amdgcn_mfma_f32_16x16x32_bf16(qf0, kf0, z, 0, 0, 0);
            z = __builtin_amdgcn_mfma_f32_16x16x32_bf16(qf1, kf1, z, 0, 0, 0);
            s[st] = z;
        }
        __builtin_amdgcn_s_setprio(0);

        // mask + scale (log2 domain)
        #pragma unroll
        for (int st = 0; st < 4; ++st) {
            const bool mk = (mb >> (st * 16 + lr)) & 1;
            #pragma unroll
            for (int i = 0; i < 4; ++i)
                s[st][i] = mk ? -1e30f : s[st][i] * SCALE;
        }
        // online softmax (rows 4g+i live across 16-lane group)
        float mt[4];
        #pragma unroll
        for (int i = 0; i < 4; ++i)
            mt[i] = fmaxf(fmaxf(s[0][i], s[1][i]), fmaxf(s[2][i], s[3][i]));
        #pragma unroll
        for (int off = 1; off < 16; off <<= 1)
            #pragma unroll
            for (int i = 0; i < 4; ++i)
                mt[i] = fmaxf(mt[i], __shfl_xor(mt[i], off));
        float alpha[4];
        #pragma unroll
        for (int i = 0; i < 4; ++i) {
            float mn = fmaxf(mrun[i], mt[i]);
            alpha[i] = EXP2F(mrun[i] - mn);
            mrun[i] = mn;
        }
        float rs[4] = {0.f, 0.f, 0.f, 0.f};
        #pragma unroll
        for (int st = 0; st < 4; ++st)
            #pragma unroll
            for (int i = 0; i < 4; ++i) {
                float p = EXP2F(s[st][i] - mrun[i]);   // masked: exp2(-1e30) = 0
                s[st][i] = p;
                rs[i] += p;
            }
        #pragma unroll
        for (int off = 1; off < 16; off <<= 1)
            #pragma unroll
            for (int i = 0; i < 4; ++i)
                rs[i] += __shfl_xor(rs[i], off);
        #pragma unroll
        for (int i = 0; i < 4; ++i)
            lrun[i] = lrun[i] * alpha[i] + rs[i];
        #pragma unroll
        for (int ni = 0; ni < 4; ++ni)
            #pragma unroll
            for (int i = 0; i < 4; ++i)
                cacc[ni][i] *= alpha[i];
        // P -> LDS (own 16-row strip; same-wave ds ordering, no barrier needed)
        #pragma unroll
        for (int st = 0; st < 4; ++st)
            #pragma unroll
            for (int i = 0; i < 4; ++i)
                *(bf16_t*)((char*)QPs + swz((wq0 + 4 * g + i) * 128 + (st * 16 + lr) * 2)) = (bf16_t)s[st][i];
        // PV
        __builtin_amdgcn_s_setprio(1);
        #pragma unroll
        for (int kk = 0; kk < 2; ++kk) {
            bf16x8 pf = *(const bf16x8*)((const char*)QPs + swz((wq0 + lr) * 128 + kk * 64 + g * 16));
            #pragma unroll
            for (int ni = 0; ni < 4; ++ni) {
                bf16x8 vf = *(const bf16x8*)((const char*)Vt + swz((ni * 16 + lr) * 128 + kk * 64 + g * 16));
                cacc[ni] = __builtin_amdgcn_mfma_f32_16x16x32_bf16(pf, vf, cacc[ni], 0, 0, 0);
            }
        }
        __builtin_amdgcn_s_setprio(0);
    }

    #pragma unroll
    for (int ni = 0; ni < 4; ++ni) {
        int dk = ni * 16 + lr;
        #pragma unroll
        for (int i = 0; i < 4; ++i) {
            int trow = q0 + wq0 + 4 * g + i;
            float v = cacc[ni][i] / lrun[i];
            ctx[((size_t)b * 2048 + trow) * 1024 + h * 64 + dk] = (bf16_t)v;
        }
    }
}

// ---------------- launch ----------------------------------------------------
extern "C" void kernel_launch(void* const* d_in, const int* in_sizes, int n_in,
                              void* d_out, int out_size, void* d_ws, size_t ws_size,
                              hipStream_t stream) {
    const float* query = (const float*)d_in[0];
    const float* key_  = (const float*)d_in[1];
    const float* value = (const float*)d_in[2];
    const unsigned char* kpm_raw = (const unsigned char*)d_in[3];
    const float* Wq = (const float*)d_in[4];
    const float* bq = (const float*)d_in[5];
    const float* Wk = (const float*)d_in[6];
    const float* bk = (const float*)d_in[7];
    const float* Wv = (const float*)d_in[8];
    const float* bv = (const float*)d_in[9];
    const float* Wo = (const float*)d_in[10];
    const float* bo = (const float*)d_in[11];
    float* out = (float*)d_out;

    char* ws = (char*)d_ws;
    size_t off = 0;
    auto alloc = [&](size_t bytes) {
        char* p = ws + off;
        off += (bytes + 255) & ~(size_t)255;
        return p;
    };
    const size_t SZ_X = (size_t)4096 * 1024 * sizeof(bf16_t);  // 8 MB
    const size_t SZ_W = (size_t)1024 * 1024 * sizeof(bf16_t);  // 2 MB
    bf16_t* xq  = (bf16_t*)alloc(SZ_X);   // xq,xk,xv contiguous
    bf16_t* xk  = (bf16_t*)alloc(SZ_X);
    bf16_t* xv  = (bf16_t*)alloc(SZ_X);
    bf16_t* wqb = (bf16_t*)alloc(SZ_W);   // wqb..wob contiguous
    bf16_t* wkb = (bf16_t*)alloc(SZ_W);
    bf16_t* wvb = (bf16_t*)alloc(SZ_W);
    bf16_t* wob = (bf16_t*)alloc(SZ_W);
    bf16_t* qhB = (bf16_t*)alloc(SZ_X);
    bf16_t* khB = (bf16_t*)alloc(SZ_X);
    bf16_t* vhB = (bf16_t*)alloc(SZ_X);
    bf16_t* ctxB = (bf16_t*)alloc(SZ_X);
    unsigned long long* mbits = (unsigned long long*)alloc(64 * sizeof(unsigned long long));
    (void)wkb; (void)wvb; (void)wob;

    prep_mask_kernel<<<1, 64, 0, stream>>>(kpm_raw, mbits);
    cvt_x3_kernel<<<6144, 256, 0, stream>>>(query, key_, value, xq);
    cvt_w4_kernel<<<2048, 256, 0, stream>>>(Wq, Wk, Wv, Wo, wqb);

    dim3 gproj(8, 32);   // N/128 x M/128
    gemm_kernel<<<gproj, 256, 0, stream>>>(xq, wqb, bq, qhB, nullptr, 0);
    gemm_kernel<<<gproj, 256, 0, stream>>>(xk, wkb, bk, khB, nullptr, 0);
    gemm_kernel<<<gproj, 256, 0, stream>>>(xv, wvb, bv, vhB, nullptr, 0);

    dim3 gattn(32, 32);  // T/64 x B*H
    attn_kernel<<<gattn, 256, 0, stream>>>(qhB, khB, vhB, mbits, ctxB);

    gemm_kernel<<<gproj, 256, 0, stream>>>(ctxB, wob, bo, nullptr, out, 1);
}

// Round 3
// 241.499 us; speedup vs baseline: 1.1801x; 1.1418x over previous
//
#include <hip/hip_runtime.h>
#include <hip/hip_bf16.h>
#include <stdint.h>

// ESPNET MultiHeadedAttention: T=2048 B=2 F=1024 H=16 DK=64
// cvt(fp32->bf16) -> 3x proj GEMM (bf16 MFMA) -> flash attn (swapped-QK^T,
// in-register softmax, swizzled LDS, K/V prefetch) -> out GEMM (fp32 out)

typedef __bf16 bf16_t;
typedef __bf16 bf16x4 __attribute__((ext_vector_type(4)));
typedef __bf16 bf16x8 __attribute__((ext_vector_type(8)));
typedef float f32x4 __attribute__((ext_vector_type(4)));

typedef const __attribute__((address_space(1))) void* gas_ptr;
typedef __attribute__((address_space(3))) void* las_ptr;

__device__ __forceinline__ void gload16(const void* g, void* lds) {
    // async global->LDS, 16B/lane; LDS dest = wave-uniform base + lane*16
    __builtin_amdgcn_global_load_lds((gas_ptr)g, (las_ptr)lds, 16, 0, 0);
}

// XOR swizzle for 128-B-row tiles: involution, moves 16B blocks, stays in-row
__device__ __forceinline__ int swz(int o) { return o ^ (((o >> 7) & 7) << 4); }

#if __has_builtin(__builtin_amdgcn_exp2f)
#define EXP2F(x) __builtin_amdgcn_exp2f(x)
#else
#define EXP2F(x) exp2f(x)
#endif
#if __has_builtin(__builtin_amdgcn_rcpf)
#define RCPF(x) __builtin_amdgcn_rcpf(x)
#else
#define RCPF(x) (1.0f / (x))
#endif

// ---------------- mask -> per-tile 64-bit masks (int32 vs byte-bool hedge) --
__global__ __launch_bounds__(64) void prep_mask_kernel(const unsigned char* __restrict__ raw,
                                                       unsigned long long* __restrict__ mbits) {
    __shared__ int s_isbyte;
    int lane = threadIdx.x;
    if (lane == 0) s_isbyte = 0;
    __syncthreads();
    int any = 0;
    for (int i = lane; i < 4096; i += 64)
        if ((i & 3) && raw[i]) any = 1;      // nonzero off-aligned byte => byte layout
    if (any) atomicOr(&s_isbyte, 1);
    __syncthreads();
    int b = lane >> 5, kt = lane & 31;       // 64 threads: one (b, key-tile) each
    unsigned long long bits = 0;
    if (s_isbyte) {
        for (int j = 0; j < 64; ++j)
            if (raw[b * 2048 + kt * 64 + j]) bits |= 1ull << j;
    } else {
        const int* ri = (const int*)raw;
        for (int j = 0; j < 64; ++j)
            if (ri[b * 2048 + kt * 64 + j]) bits |= 1ull << j;
    }
    mbits[lane] = bits;
}

// ---------------- fp32 [T,B,F] -> bf16 [B,T,F], all 3 tensors --------------
__global__ __launch_bounds__(256) void cvt_x3_kernel(const float* __restrict__ q,
                                                     const float* __restrict__ k,
                                                     const float* __restrict__ v,
                                                     bf16_t* __restrict__ dst) {
    int idx = blockIdx.x * 256 + threadIdx.x;
    int which = idx >> 19;                   // 524288 threads per tensor
    int loc = idx & 524287;
    const float* src = which == 0 ? q : which == 1 ? k : v;
    int e0 = loc * 8;
    int t = e0 >> 11, r = e0 & 2047, b = r >> 10, f = r & 1023;
    const float4* s = (const float4*)(src + e0);
    float4 a = s[0], c = s[1];
    bf16x8 o;
    o[0] = (bf16_t)a.x; o[1] = (bf16_t)a.y; o[2] = (bf16_t)a.z; o[3] = (bf16_t)a.w;
    o[4] = (bf16_t)c.x; o[5] = (bf16_t)c.y; o[6] = (bf16_t)c.z; o[7] = (bf16_t)c.w;
    *(bf16x8*)(dst + (size_t)which * 4194304 + ((size_t)b * 2048 + t) * 1024 + f) = o;
}

// ---------------- fp32 -> bf16, all 4 weight matrices (contiguous dst) ------
__global__ __launch_bounds__(256) void cvt_w4_kernel(const float* __restrict__ wq,
                                                     const float* __restrict__ wk,
                                                     const float* __restrict__ wv,
                                                     const float* __restrict__ wo,
                                                     bf16_t* __restrict__ dst) {
    int idx = blockIdx.x * 256 + threadIdx.x;
    int which = idx >> 17;                   // 131072 threads per matrix
    int loc = idx & 131071;
    const float* src = which == 0 ? wq : which == 1 ? wk : which == 2 ? wv : wo;
    int e0 = loc * 8;
    const float4* s = (const float4*)(src + e0);
    float4 a = s[0], c = s[1];
    bf16x8 o;
    o[0] = (bf16_t)a.x; o[1] = (bf16_t)a.y; o[2] = (bf16_t)a.z; o[3] = (bf16_t)a.w;
    o[4] = (bf16_t)c.x; o[5] = (bf16_t)c.y; o[6] = (bf16_t)c.z; o[7] = (bf16_t)c.w;
    *(bf16x8*)(dst + (size_t)which * 1048576 + e0) = o;
}

// ---------------- GEMM: C = A[M x 1024] * Bw[1024 x 1024]^T + bias ----------
// mode 0: out bf16 scattered to [B,H,T,DK]; mode 1: out fp32 at [T,B,F]
__global__ __launch_bounds__(256) void gemm_kernel(const bf16_t* __restrict__ A,
                                                   const bf16_t* __restrict__ Bw,
                                                   const float* __restrict__ bias,
                                                   bf16_t* __restrict__ outb,
                                                   float* __restrict__ outf,
                                                   int mode) {
    __shared__ __align__(16) bf16_t Asm[128 * 32];
    __shared__ __align__(16) bf16_t Bsm[128 * 32];
    const int tid = threadIdx.x;
    const int wave = tid >> 6, lane = tid & 63;
    const int g = lane >> 4, lr = lane & 15;
    const int m0 = blockIdx.y * 128, n0 = blockIdx.x * 128;
    const int wm = (wave >> 1) * 64, wn = (wave & 1) * 64;
    const int srow = wave * 32 + (lane >> 2);
    const int scol = (lane & 3) * 8;

    f32x4 acc[4][4] = {};

    for (int k0 = 0; k0 < 1024; k0 += 32) {
        __syncthreads();
        gload16(A  + (size_t)(m0 + srow) * 1024 + k0 + scol,      (char*)Asm + wave * 2048);
        gload16(A  + (size_t)(m0 + srow + 16) * 1024 + k0 + scol, (char*)Asm + wave * 2048 + 1024);
        gload16(Bw + (size_t)(n0 + srow) * 1024 + k0 + scol,      (char*)Bsm + wave * 2048);
        gload16(Bw + (size_t)(n0 + srow + 16) * 1024 + k0 + scol, (char*)Bsm + wave * 2048 + 1024);
        __syncthreads();

        bf16x8 af[4], bfr[4];
        #pragma unroll
        for (int mi = 0; mi < 4; ++mi)
            af[mi] = *(const bf16x8*)(Asm + (wm + mi * 16 + lr) * 32 + g * 8);
        #pragma unroll
        for (int ni = 0; ni < 4; ++ni)
            bfr[ni] = *(const bf16x8*)(Bsm + (wn + ni * 16 + lr) * 32 + g * 8);
        #pragma unroll
        for (int mi = 0; mi < 4; ++mi)
            #pragma unroll
            for (int ni = 0; ni < 4; ++ni)
                acc[mi][ni] = __builtin_amdgcn_mfma_f32_16x16x32_bf16(af[mi], bfr[ni], acc[mi][ni], 0, 0, 0);
    }

    #pragma unroll
    for (int mi = 0; mi < 4; ++mi) {
        #pragma unroll
        for (int ni = 0; ni < 4; ++ni) {
            int n = n0 + wn + ni * 16 + lr;
            float bs = bias[n];
            #pragma unroll
            for (int i = 0; i < 4; ++i) {
                int m = m0 + wm + mi * 16 + 4 * g + i;
                float v = acc[mi][ni][i] + bs;
                int b = m >> 11, t = m & 2047;
                if (mode == 0) {
                    int hh = n >> 6, dk = n & 63;
                    outb[((size_t)(b * 16 + hh) * 2048 + t) * 64 + dk] = (bf16_t)v;
                } else {
                    outf[(size_t)t * 2048 + b * 1024 + n] = v;
                }
            }
        }
    }
}

// ---------------- flash attention (swapped QK^T, in-register softmax) -------
// grid (T/64, B*H); 4 waves; wave owns 16 q-rows; lane owns query lr, keys 16st+4g+i.
// LDS = 16K (K dbuf, Q staged via Ks[1]) + 8K (Vt) = 24 KB
__global__ __launch_bounds__(256) void attn_kernel(const bf16_t* __restrict__ qh,
                                                   const bf16_t* __restrict__ kh,
                                                   const bf16_t* __restrict__ vh,
                                                   const unsigned long long* __restrict__ mbits,
                                                   bf16_t* __restrict__ ctx) {
    __shared__ __align__(16) bf16_t Ks[2][64 * 64];    // double-buffered K (swizzled)
    __shared__ __align__(16) bf16_t Vt[64 * 64];       // V^T [dk][key] (swizzled)

    const int tid = threadIdx.x;
    const int wave = tid >> 6, lane = tid & 63;
    const int g = lane >> 4, lr = lane & 15;
    const int bh = blockIdx.y;
    const int b = bh >> 4, h = bh & 15;
    const int q0 = blockIdx.x * 64;
    const bf16_t* Qg = qh + ((size_t)bh * 2048 + q0) * 64;
    const bf16_t* Kg = kh + (size_t)bh * 2048 * 64;
    const bf16_t* Vg = vh + (size_t)bh * 2048 * 64;
    const unsigned long long* mbp = mbits + b * 32;

    const int dstw = wave * 2048;            // wave's 2KB staging chunk (byte offset)
    const int dl = dstw + lane * 16;
    const int wq0 = wave * 16;

    // stage Q through Ks[1] (pre-swizzled source, linear dest), read to regs
    gload16((const char*)Qg + swz(dl),        (char*)Ks[1] + dstw);
    gload16((const char*)Qg + swz(dl + 1024), (char*)Ks[1] + dstw + 1024);
    __syncthreads();
    bf16x8 qf0 = *(const bf16x8*)((const char*)Ks[1] + swz((wq0 + lr) * 128 + g * 16));
    bf16x8 qf1 = *(const bf16x8*)((const char*)Ks[1] + swz((wq0 + lr) * 128 + 64 + g * 16));

    // prologue prefetch: K0 -> Ks[0], V0 -> regs
    gload16((const char*)Kg + swz(dl),        (char*)Ks[0] + dstw);
    gload16((const char*)Kg + swz(dl + 1024), (char*)Ks[0] + dstw + 1024);
    bf16x8 v0 = *(const bf16x8*)(Vg + lane * 64 + wave * 8);
    bf16x8 v1 = *(const bf16x8*)(Vg + lane * 64 + (wave + 4) * 8);

    f32x4 cacc[4] = {};
    float mrun = -1e30f, lrun = 0.f;
    const float SCALE = 0.125f * 1.44269504f;   // 1/sqrt(64) * log2(e)

    for (int kt = 0; kt < 32; ++kt) {
        const int cur = kt & 1;
        __syncthreads();   // K[kt] staged + all waves' qf/prev-LDS reads done
        const unsigned long long mb = mbp[kt];

        // write V^T tile (swizzled [dk][key]); wave owns dk rows [8w,8w+8) & [8w+32,..)
        #pragma unroll
        for (int j = 0; j < 8; ++j) {
            *(bf16_t*)((char*)Vt + swz((wave * 8 + j) * 128 + lane * 2))       = v0[j];
            *(bf16_t*)((char*)Vt + swz(((wave + 4) * 8 + j) * 128 + lane * 2)) = v1[j];
        }
        __syncthreads();   // Vt visible (lgkm-only drain)

        // prefetch next K (async -> other buffer) and V (-> regs)
        const int nx = (kt < 31) ? kt + 1 : 31;
        const char* Kn = (const char*)(Kg + nx * 4096);
        gload16(Kn + swz(dl),        (char*)Ks[cur ^ 1] + dstw);
        gload16(Kn + swz(dl + 1024), (char*)Ks[cur ^ 1] + dstw + 1024);
        const bf16_t* Vn = Vg + nx * 4096;
        v0 = *(const bf16x8*)(Vn + lane * 64 + wave * 8);
        v1 = *(const bf16x8*)(Vn + lane * 64 + (wave + 4) * 8);

        // S^T = K Q^T : lane holds S^T[key=16st+4g+i][q=lr]
        const char* Kc = (const char*)Ks[cur];
        f32x4 s[4];
        __builtin_amdgcn_s_setprio(1);
        #pragma unroll
        for (int st = 0; st < 4; ++st) {
            bf16x8 kf0 = *(const bf16x8*)(Kc + swz((st * 16 + lr) * 128 + g * 16));
            bf16x8 kf1 = *(const bf16x8*)(Kc + swz((st * 16 + lr) * 128 + 64 + g * 16));
            f32x4 z = {};
            z = __builtin_amdgcn_mfma_f32_16x16x32_bf16(kf0, qf0, z, 0, 0, 0);
            z = __builtin_amdgcn_mfma_f32_16x16x32_bf16(kf1, qf1, z, 0, 0, 0);
            s[st] = z;
        }
        __builtin_amdgcn_s_setprio(0);

        // mask + scale (log2 domain); key bit = 16st + 4g + i
        const unsigned long long mq = mb >> (4 * g);
        const unsigned mlo = (unsigned)mq, mhi = (unsigned)(mq >> 32);
        #pragma unroll
        for (int st = 0; st < 4; ++st) {
            #pragma unroll
            for (int i = 0; i < 4; ++i) {
                const bool mk = ((st < 2 ? mlo >> (16 * st + i) : mhi >> (16 * (st - 2) + i)) & 1);
                s[st][i] = mk ? -1e30f : s[st][i] * SCALE;
            }
        }
        // softmax over keys: 15 in-lane + 2 cross-lane (g axis)
        float mt0 = fmaxf(fmaxf(s[0][0], s[0][1]), fmaxf(s[0][2], s[0][3]));
        float mt1 = fmaxf(fmaxf(s[1][0], s[1][1]), fmaxf(s[1][2], s[1][3]));
        float mt2 = fmaxf(fmaxf(s[2][0], s[2][1]), fmaxf(s[2][2], s[2][3]));
        float mt3 = fmaxf(fmaxf(s[3][0], s[3][1]), fmaxf(s[3][2], s[3][3]));
        float mt = fmaxf(fmaxf(mt0, mt1), fmaxf(mt2, mt3));
        mt = fmaxf(mt, __shfl_xor(mt, 16));
        mt = fmaxf(mt, __shfl_xor(mt, 32));
        const float mn = fmaxf(mrun, mt);
        const float alpha = EXP2F(mrun - mn);
        mrun = mn;
        float rsum = 0.f;
        #pragma unroll
        for (int st = 0; st < 4; ++st)
            #pragma unroll
            for (int i = 0; i < 4; ++i) {
                float p = EXP2F(s[st][i] - mn);   // masked: exp2(-1e30) = 0
                s[st][i] = p;
                rsum += p;
            }
        rsum += __shfl_xor(rsum, 16);
        rsum += __shfl_xor(rsum, 32);
        lrun = lrun * alpha + rsum;
        #pragma unroll
        for (int ni = 0; ni < 4; ++ni)
            #pragma unroll
            for (int i = 0; i < 4; ++i)
                cacc[ni][i] *= alpha;
        // pack P^T B-fragments in-register: slot j -> key 16*(j>>2) + 4g + (j&3) (+32kk)
        bf16x8 pb[2];
        #pragma unroll
        for (int kk = 0; kk < 2; ++kk)
            #pragma unroll
            for (int j = 0; j < 8; ++j)
                pb[kk][j] = (bf16_t)s[2 * kk + (j >> 2)][j & 3];
        // PV: ctx^T[d][q] += V^T[d][key] * P^T[key][q]; A k-slots match sigma
        __builtin_amdgcn_s_setprio(1);
        #pragma unroll
        for (int kk = 0; kk < 2; ++kk) {
            #pragma unroll
            for (int ni = 0; ni < 4; ++ni) {
                union { bf16x8 v8; struct { bf16x4 lo, hi; } p; } u;
                u.p.lo = *(const bf16x4*)((const char*)Vt + swz((ni * 16 + lr) * 128 + kk * 64 + g * 8));
                u.p.hi = *(const bf16x4*)((const char*)Vt + swz((ni * 16 + lr) * 128 + kk * 64 + g * 8 + 32));
                cacc[ni] = __builtin_amdgcn_mfma_f32_16x16x32_bf16(u.v8, pb[kk], cacc[ni], 0, 0, 0);
            }
        }
        __builtin_amdgcn_s_setprio(0);
    }

    // epilogue: ctx^T -> ctx; lane owns query lr, d = ni*16 + 4g + i (4 contiguous)
    const float rl = RCPF(lrun);
    const int trow = q0 + wq0 + lr;
    #pragma unroll
    for (int ni = 0; ni < 4; ++ni) {
        bf16x4 o;
        #pragma unroll
        for (int i = 0; i < 4; ++i)
            o[i] = (bf16_t)(cacc[ni][i] * rl);
        *(bf16x4*)(ctx + ((size_t)b * 2048 + trow) * 1024 + h * 64 + ni * 16 + 4 * g) = o;
    }
}

// ---------------- launch ----------------------------------------------------
extern "C" void kernel_launch(void* const* d_in, const int* in_sizes, int n_in,
                              void* d_out, int out_size, void* d_ws, size_t ws_size,
                              hipStream_t stream) {
    const float* query = (const float*)d_in[0];
    const float* key_  = (const float*)d_in[1];
    const float* value = (const float*)d_in[2];
    const unsigned char* kpm_raw = (const unsigned char*)d_in[3];
    const float* Wq = (const float*)d_in[4];
    const float* bq = (const float*)d_in[5];
    const float* Wk = (const float*)d_in[6];
    const float* bk = (const float*)d_in[7];
    const float* Wv = (const float*)d_in[8];
    const float* bv = (const float*)d_in[9];
    const float* Wo = (const float*)d_in[10];
    const float* bo = (const float*)d_in[11];
    float* out = (float*)d_out;

    char* ws = (char*)d_ws;
    size_t off = 0;
    auto alloc = [&](size_t bytes) {
        char* p = ws + off;
        off += (bytes + 255) & ~(size_t)255;
        return p;
    };
    const size_t SZ_X = (size_t)4096 * 1024 * sizeof(bf16_t);  // 8 MB
    const size_t SZ_W = (size_t)1024 * 1024 * sizeof(bf16_t);  // 2 MB
    bf16_t* xq  = (bf16_t*)alloc(SZ_X);   // xq,xk,xv contiguous
    bf16_t* xk  = (bf16_t*)alloc(SZ_X);
    bf16_t* xv  = (bf16_t*)alloc(SZ_X);
    bf16_t* wqb = (bf16_t*)alloc(SZ_W);   // wqb..wob contiguous
    bf16_t* wkb = (bf16_t*)alloc(SZ_W);
    bf16_t* wvb = (bf16_t*)alloc(SZ_W);
    bf16_t* wob = (bf16_t*)alloc(SZ_W);
    bf16_t* qhB = (bf16_t*)alloc(SZ_X);
    bf16_t* khB = (bf16_t*)alloc(SZ_X);
    bf16_t* vhB = (bf16_t*)alloc(SZ_X);
    bf16_t* ctxB = (bf16_t*)alloc(SZ_X);
    unsigned long long* mbits = (unsigned long long*)alloc(64 * sizeof(unsigned long long));
    (void)wkb; (void)wvb; (void)wob;

    prep_mask_kernel<<<1, 64, 0, stream>>>(kpm_raw, mbits);
    cvt_x3_kernel<<<6144, 256, 0, stream>>>(query, key_, value, xq);
    cvt_w4_kernel<<<2048, 256, 0, stream>>>(Wq, Wk, Wv, Wo, wqb);

    dim3 gproj(8, 32);   // N/128 x M/128
    gemm_kernel<<<gproj, 256, 0, stream>>>(xq, wqb, bq, qhB, nullptr, 0);
    gemm_kernel<<<gproj, 256, 0, stream>>>(xk, wkb, bk, khB, nullptr, 0);
    gemm_kernel<<<gproj, 256, 0, stream>>>(xv, wvb, bv, vhB, nullptr, 0);

    dim3 gattn(32, 32);  // T/64 x B*H
    attn_kernel<<<gattn, 256, 0, stream>>>(qhB, khB, vhB, mbits, ctxB);

    gemm_kernel<<<gproj, 256, 0, stream>>>(ctxB, wob, bo, nullptr, out, 1);
}

// Round 4
// 169.613 us; speedup vs baseline: 1.6802x; 1.4238x over previous
//
#include <hip/hip_runtime.h>
#include <hip/hip_bf16.h>
#include <stdint.h>

// ESPNET MultiHeadedAttention: T=2048 B=2 F=1024 H=16 DK=64
// cvt(fp32->bf16) -> QKV proj GEMM (one z=3 dispatch, Q pre-scaled) ->
// flash attn (swapped QK^T, in-reg softmax, defer-max, V via ds_read_b64_tr_b16,
// single barrier/iter) -> out GEMM (fp32 out)

typedef __bf16 bf16_t;
typedef __bf16 bf16x4 __attribute__((ext_vector_type(4)));
typedef __bf16 bf16x8 __attribute__((ext_vector_type(8)));
typedef float f32x4 __attribute__((ext_vector_type(4)));
typedef unsigned int u32x2 __attribute__((ext_vector_type(2)));

typedef const __attribute__((address_space(1))) void* gas_ptr;
typedef __attribute__((address_space(3))) void* las_ptr;

__device__ __forceinline__ void gload16(const void* g, void* lds) {
    // async global->LDS, 16B/lane; LDS dest = wave-uniform base + lane*16
    __builtin_amdgcn_global_load_lds((gas_ptr)g, (las_ptr)lds, 16, 0, 0);
}

// XOR swizzle for 128-B-row tiles: involution, moves 16B blocks, stays in-row
__device__ __forceinline__ int swz(int o) { return o ^ (((o >> 7) & 7) << 4); }

// V staging pre-permutation: 16B chunk c of subtiled LDS [key/4][d/16][4][16]
// comes from global byte offset (key*128 + d*2) of the 64x64 V tile.
__device__ __forceinline__ int gofs(int c) {
    return ((c >> 5) << 9) + (((c >> 1) & 3) << 7) + (((c >> 3) & 3) << 5) + ((c & 1) << 4);
}

#define TRREAD(dst, addr, IMM) \
    asm volatile("ds_read_b64_tr_b16 %0, %1 offset:" #IMM : "=v"(dst) : "v"(addr))

#if __has_builtin(__builtin_amdgcn_exp2f)
#define EXP2F(x) __builtin_amdgcn_exp2f(x)
#else
#define EXP2F(x) exp2f(x)
#endif
#if __has_builtin(__builtin_amdgcn_rcpf)
#define RCPF(x) __builtin_amdgcn_rcpf(x)
#else
#define RCPF(x) (1.0f / (x))
#endif

// ---------------- mask -> per-tile 64-bit masks (int32 vs byte-bool hedge) --
__global__ __launch_bounds__(64) void prep_mask_kernel(const unsigned char* __restrict__ raw,
                                                       unsigned long long* __restrict__ mbits) {
    __shared__ int s_isbyte;
    int lane = threadIdx.x;
    if (lane == 0) s_isbyte = 0;
    __syncthreads();
    int any = 0;
    for (int i = lane; i < 4096; i += 64)
        if ((i & 3) && raw[i]) any = 1;      // nonzero off-aligned byte => byte layout
    if (any) atomicOr(&s_isbyte, 1);
    __syncthreads();
    int b = lane >> 5, kt = lane & 31;       // 64 threads: one (b, key-tile) each
    unsigned long long bits = 0;
    if (s_isbyte) {
        for (int j = 0; j < 64; ++j)
            if (raw[b * 2048 + kt * 64 + j]) bits |= 1ull << j;
    } else {
        const int* ri = (const int*)raw;
        for (int j = 0; j < 64; ++j)
            if (ri[b * 2048 + kt * 64 + j]) bits |= 1ull << j;
    }
    mbits[lane] = bits;
}

// ---------------- fp32 [T,B,F] -> bf16 [B,T,F], all 3 tensors --------------
__global__ __launch_bounds__(256) void cvt_x3_kernel(const float* __restrict__ q,
                                                     const float* __restrict__ k,
                                                     const float* __restrict__ v,
                                                     bf16_t* __restrict__ dst) {
    int idx = blockIdx.x * 256 + threadIdx.x;
    int which = idx >> 19;                   // 524288 threads per tensor
    int loc = idx & 524287;
    const float* src = which == 0 ? q : which == 1 ? k : v;
    int e0 = loc * 8;
    int t = e0 >> 11, r = e0 & 2047, b = r >> 10, f = r & 1023;
    const float4* s = (const float4*)(src + e0);
    float4 a = s[0], c = s[1];
    bf16x8 o;
    o[0] = (bf16_t)a.x; o[1] = (bf16_t)a.y; o[2] = (bf16_t)a.z; o[3] = (bf16_t)a.w;
    o[4] = (bf16_t)c.x; o[5] = (bf16_t)c.y; o[6] = (bf16_t)c.z; o[7] = (bf16_t)c.w;
    *(bf16x8*)(dst + (size_t)which * 4194304 + ((size_t)b * 2048 + t) * 1024 + f) = o;
}

// ---------------- fp32 -> bf16, all 4 weight matrices (contiguous dst) ------
__global__ __launch_bounds__(256) void cvt_w4_kernel(const float* __restrict__ wq,
                                                     const float* __restrict__ wk,
                                                     const float* __restrict__ wv,
                                                     const float* __restrict__ wo,
                                                     bf16_t* __restrict__ dst) {
    int idx = blockIdx.x * 256 + threadIdx.x;
    int which = idx >> 17;                   // 131072 threads per matrix
    int loc = idx & 131071;
    const float* src = which == 0 ? wq : which == 1 ? wk : which == 2 ? wv : wo;
    int e0 = loc * 8;
    const float4* s = (const float4*)(src + e0);
    float4 a = s[0], c = s[1];
    bf16x8 o;
    o[0] = (bf16_t)a.x; o[1] = (bf16_t)a.y; o[2] = (bf16_t)a.z; o[3] = (bf16_t)a.w;
    o[4] = (bf16_t)c.x; o[5] = (bf16_t)c.y; o[6] = (bf16_t)c.z; o[7] = (bf16_t)c.w;
    *(bf16x8*)(dst + (size_t)which * 1048576 + e0) = o;
}

// ---------------- GEMM: C = A[M x 1024] * Bw[1024 x 1024]^T + bias ----------
// blockIdx.z selects the projection (A += z*4M elems, Bw += z*1M, bias b_z).
// mode 0: out bf16 scattered to [B,H,T,DK] (+z*4M); z==0 output pre-scaled by
//         0.125*log2(e) (Q score scale folded in). mode 1: out fp32 at [T,B,F].
__global__ __launch_bounds__(256) void gemm_kernel(const bf16_t* __restrict__ A0,
                                                   const bf16_t* __restrict__ Bw0,
                                                   const float* __restrict__ b0,
                                                   const float* __restrict__ b1,
                                                   const float* __restrict__ b2,
                                                   bf16_t* __restrict__ outb,
                                                   float* __restrict__ outf,
                                                   int mode) {
    __shared__ __align__(16) bf16_t Asm[128 * 32];
    __shared__ __align__(16) bf16_t Bsm[128 * 32];
    const int tid = threadIdx.x;
    const int wave = tid >> 6, lane = tid & 63;
    const int g = lane >> 4, lr = lane & 15;
    const int z = blockIdx.z;
    const bf16_t* A  = A0 + (size_t)z * 4194304;
    const bf16_t* Bw = Bw0 + (size_t)z * 1048576;
    const float* bias = z == 0 ? b0 : z == 1 ? b1 : b2;
    const float qsc = (mode == 0 && z == 0) ? 0.18033688f : 1.0f;  // 0.125*log2e
    const int m0 = blockIdx.y * 128, n0 = blockIdx.x * 128;
    const int wm = (wave >> 1) * 64, wn = (wave & 1) * 64;
    const int srow = wave * 32 + (lane >> 2);
    const int scol = (lane & 3) * 8;

    f32x4 acc[4][4] = {};

    for (int k0 = 0; k0 < 1024; k0 += 32) {
        __syncthreads();
        gload16(A  + (size_t)(m0 + srow) * 1024 + k0 + scol,      (char*)Asm + wave * 2048);
        gload16(A  + (size_t)(m0 + srow + 16) * 1024 + k0 + scol, (char*)Asm + wave * 2048 + 1024);
        gload16(Bw + (size_t)(n0 + srow) * 1024 + k0 + scol,      (char*)Bsm + wave * 2048);
        gload16(Bw + (size_t)(n0 + srow + 16) * 1024 + k0 + scol, (char*)Bsm + wave * 2048 + 1024);
        __syncthreads();

        bf16x8 af[4], bfr[4];
        #pragma unroll
        for (int mi = 0; mi < 4; ++mi)
            af[mi] = *(const bf16x8*)(Asm + (wm + mi * 16 + lr) * 32 + g * 8);
        #pragma unroll
        for (int ni = 0; ni < 4; ++ni)
            bfr[ni] = *(const bf16x8*)(Bsm + (wn + ni * 16 + lr) * 32 + g * 8);
        #pragma unroll
        for (int mi = 0; mi < 4; ++mi)
            #pragma unroll
            for (int ni = 0; ni < 4; ++ni)
                acc[mi][ni] = __builtin_amdgcn_mfma_f32_16x16x32_bf16(af[mi], bfr[ni], acc[mi][ni], 0, 0, 0);
    }

    #pragma unroll
    for (int mi = 0; mi < 4; ++mi) {
        #pragma unroll
        for (int ni = 0; ni < 4; ++ni) {
            int n = n0 + wn + ni * 16 + lr;
            float bs = bias[n];
            #pragma unroll
            for (int i = 0; i < 4; ++i) {
                int m = m0 + wm + mi * 16 + 4 * g + i;
                float v = (acc[mi][ni][i] + bs) * qsc;
                int b = m >> 11, t = m & 2047;
                if (mode == 0) {
                    int hh = n >> 6, dk = n & 63;
                    outb[(size_t)z * 4194304 + ((size_t)(b * 16 + hh) * 2048 + t) * 64 + dk] = (bf16_t)v;
                } else {
                    outf[(size_t)t * 2048 + b * 1024 + n] = v;
                }
            }
        }
    }
}

// ---------------- flash attention ------------------------------------------
// grid (T/64, B*H); 4 waves; wave owns 16 q-rows; lane owns query lr.
// Swapped QK^T (lane-local softmax), V via subtiled LDS + ds_read_b64_tr_b16.
// LDS = 16K (K dbuf; Q staged via Ks[1]) + 16K (V dbuf) = 32 KB; 1 barrier/iter.
__global__ __launch_bounds__(256, 4) void attn_kernel(const bf16_t* __restrict__ qh,
                                                      const bf16_t* __restrict__ kh,
                                                      const bf16_t* __restrict__ vh,
                                                      const unsigned long long* __restrict__ mbits,
                                                      bf16_t* __restrict__ ctx) {
    __shared__ __align__(16) bf16_t Ks[2][64 * 64];    // K dbuf, swizzled 128B rows
    __shared__ __align__(16) bf16_t Vs[2][64 * 64];    // V dbuf, subtiled [kb][dq][4][16]

    const int tid = threadIdx.x;
    const int wave = tid >> 6, lane = tid & 63;
    const int g = lane >> 4, lr = lane & 15;
    const int bh = blockIdx.y;
    const int b = bh >> 4, h = bh & 15;
    const int q0 = blockIdx.x * 64;
    const bf16_t* Qg = qh + ((size_t)bh * 2048 + q0) * 64;
    const bf16_t* Kg = kh + (size_t)bh * 2048 * 64;
    const bf16_t* Vg = vh + (size_t)bh * 2048 * 64;
    const unsigned long long* mbp = mbits + b * 32;

    const int dstw = wave * 2048;            // wave's 2KB staging chunk (byte offset)
    const int dl = dstw + lane * 16;
    const int wq0 = wave * 16;
    const int vs0 = gofs(wave * 128 + lane);        // V source pre-permutation (bytes)
    const int vs1 = gofs(wave * 128 + 64 + lane);

    // stage Q through Ks[1] (pre-swizzled source, linear dest), read to regs.
    // Q was pre-scaled by 0.125*log2e at projection.
    gload16((const char*)Qg + swz(dl),        (char*)Ks[1] + dstw);
    gload16((const char*)Qg + swz(dl + 1024), (char*)Ks[1] + dstw + 1024);
    __syncthreads();
    bf16x8 qf0 = *(const bf16x8*)((const char*)Ks[1] + swz((wq0 + lr) * 128 + g * 16));
    bf16x8 qf1 = *(const bf16x8*)((const char*)Ks[1] + swz((wq0 + lr) * 128 + 64 + g * 16));

    // prologue prefetch: K0 -> Ks[0], V0 -> Vs[0] (subtiled via source permutation)
    gload16((const char*)Kg + swz(dl),        (char*)Ks[0] + dstw);
    gload16((const char*)Kg + swz(dl + 1024), (char*)Ks[0] + dstw + 1024);
    gload16((const char*)Vg + vs0,            (char*)Vs[0] + dstw);
    gload16((const char*)Vg + vs1,            (char*)Vs[0] + dstw + 1024);

    f32x4 cacc[4] = {};
    float mrun = -1e30f, lrun = 0.f;
    const unsigned vbase = (unsigned)(unsigned long long)(las_ptr)&Vs[0][0] + g * 512 + lr * 8;

    for (int kt = 0; kt < 32; ++kt) {
        const int cur = kt & 1;
        __syncthreads();   // drains vmcnt: K[kt],V[kt] staged; all prev-buf reads done
        const unsigned long long mb = mbp[kt];

        // prefetch next K/V into the other buffers (in flight across compute)
        const int nx = (kt < 31) ? kt + 1 : 31;
        const char* Kn = (const char*)(Kg + nx * 4096);
        const char* Vn = (const char*)(Vg + nx * 4096);
        gload16(Kn + swz(dl),        (char*)Ks[cur ^ 1] + dstw);
        gload16(Kn + swz(dl + 1024), (char*)Ks[cur ^ 1] + dstw + 1024);
        gload16(Vn + vs0,            (char*)Vs[cur ^ 1] + dstw);
        gload16(Vn + vs1,            (char*)Vs[cur ^ 1] + dstw + 1024);

        // S^T = K Q^T : lane holds S^T[key=16st+4g+i][q=lr]  (already score-scaled)
        const char* Kc = (const char*)Ks[cur];
        f32x4 s[4];
        __builtin_amdgcn_s_setprio(1);
        #pragma unroll
        for (int st = 0; st < 4; ++st) {
            bf16x8 kf0 = *(const bf16x8*)(Kc + swz((st * 16 + lr) * 128 + g * 16));
            bf16x8 kf1 = *(const bf16x8*)(Kc + swz((st * 16 + lr) * 128 + 64 + g * 16));
            f32x4 z = {};
            z = __builtin_amdgcn_mfma_f32_16x16x32_bf16(kf0, qf0, z, 0, 0, 0);
            z = __builtin_amdgcn_mfma_f32_16x16x32_bf16(kf1, qf1, z, 0, 0, 0);
            s[st] = z;
        }
        __builtin_amdgcn_s_setprio(0);

        // key padding mask; key bit = 16st + 4g + i
        const unsigned long long mq = mb >> (4 * g);
        const unsigned mlo = (unsigned)mq, mhi = (unsigned)(mq >> 32);
        #pragma unroll
        for (int st = 0; st < 4; ++st) {
            #pragma unroll
            for (int i = 0; i < 4; ++i) {
                const bool mk = ((st < 2 ? mlo >> (16 * st + i) : mhi >> (16 * (st - 2) + i)) & 1);
                if (mk) s[st][i] = -1e30f;
            }
        }
        // tile max (15 in-lane + 2 cross-lane)
        float mt0 = fmaxf(fmaxf(s[0][0], s[0][1]), fmaxf(s[0][2], s[0][3]));
        float mt1 = fmaxf(fmaxf(s[1][0], s[1][1]), fmaxf(s[1][2], s[1][3]));
        float mt2 = fmaxf(fmaxf(s[2][0], s[2][1]), fmaxf(s[2][2], s[2][3]));
        float mt3 = fmaxf(fmaxf(s[3][0], s[3][1]), fmaxf(s[3][2], s[3][3]));
        float mt = fmaxf(fmaxf(mt0, mt1), fmaxf(mt2, mt3));
        mt = fmaxf(mt, __shfl_xor(mt, 16));
        mt = fmaxf(mt, __shfl_xor(mt, 32));
        // defer-max (T13): rescale only when max grew by >8 (log2 units); P <= 256
        if (__any(mt > mrun + 8.f)) {
            const float mn = fmaxf(mrun, mt);
            const float al = EXP2F(mrun - mn);
            mrun = mn;
            lrun *= al;
            #pragma unroll
            for (int ni = 0; ni < 4; ++ni)
                #pragma unroll
                for (int i = 0; i < 4; ++i)
                    cacc[ni][i] *= al;
        }
        float rsum = 0.f;
        #pragma unroll
        for (int st = 0; st < 4; ++st)
            #pragma unroll
            for (int i = 0; i < 4; ++i) {
                float p = EXP2F(s[st][i] - mrun);   // masked: exp2(-1e30)=0 (mrun finite)
                s[st][i] = p;
                rsum += p;
            }
        rsum += __shfl_xor(rsum, 16);
        rsum += __shfl_xor(rsum, 32);
        lrun += rsum;
        // pack P^T B-fragments: slot j -> key 32kk + 16(j>>2) + 4g + (j&3)
        bf16x8 pb[2];
        #pragma unroll
        for (int kk = 0; kk < 2; ++kk)
            #pragma unroll
            for (int j = 0; j < 8; ++j)
                pb[kk][j] = (bf16_t)s[2 * kk + (j >> 2)][j & 3];

        // PV: A = V^T fragments via hardware transpose read (16 x b64_tr_b16)
        const unsigned vb = vbase + (cur ? 8192u : 0u);
        u32x2 t[2][2][4];
        TRREAD(t[0][0][0], vb, 0);    TRREAD(t[0][0][1], vb, 128);
        TRREAD(t[0][0][2], vb, 256);  TRREAD(t[0][0][3], vb, 384);
        TRREAD(t[0][1][0], vb, 2048); TRREAD(t[0][1][1], vb, 2176);
        TRREAD(t[0][1][2], vb, 2304); TRREAD(t[0][1][3], vb, 2432);
        TRREAD(t[1][0][0], vb, 4096); TRREAD(t[1][0][1], vb, 4224);
        TRREAD(t[1][0][2], vb, 4352); TRREAD(t[1][0][3], vb, 4480);
        TRREAD(t[1][1][0], vb, 6144); TRREAD(t[1][1][1], vb, 6272);
        TRREAD(t[1][1][2], vb, 6400); TRREAD(t[1][1][3], vb, 6528);
        asm volatile("s_waitcnt lgkmcnt(0)" ::: "memory");
        __builtin_amdgcn_sched_barrier(0);   // rule 18: keep MFMAs after the wait
        __builtin_amdgcn_s_setprio(1);
        #pragma unroll
        for (int kk = 0; kk < 2; ++kk) {
            #pragma unroll
            for (int ni = 0; ni < 4; ++ni) {
                union { u32x2 q[2]; bf16x8 v8; } u;
                u.q[0] = t[kk][0][ni];
                u.q[1] = t[kk][1][ni];
                cacc[ni] = __builtin_amdgcn_mfma_f32_16x16x32_bf16(u.v8, pb[kk], cacc[ni], 0, 0, 0);
            }
        }
        __builtin_amdgcn_s_setprio(0);
    }

    // epilogue: ctx^T -> ctx; lane owns query lr, d = ni*16 + 4g + i (4 contiguous)
    const float rl = RCPF(lrun);
    const int trow = q0 + wq0 + lr;
    #pragma unroll
    for (int ni = 0; ni < 4; ++ni) {
        bf16x4 o;
        #pragma unroll
        for (int i = 0; i < 4; ++i)
            o[i] = (bf16_t)(cacc[ni][i] * rl);
        *(bf16x4*)(ctx + ((size_t)b * 2048 + trow) * 1024 + h * 64 + ni * 16 + 4 * g) = o;
    }
}

// ---------------- launch ----------------------------------------------------
extern "C" void kernel_launch(void* const* d_in, const int* in_sizes, int n_in,
                              void* d_out, int out_size, void* d_ws, size_t ws_size,
                              hipStream_t stream) {
    const float* query = (const float*)d_in[0];
    const float* key_  = (const float*)d_in[1];
    const float* value = (const float*)d_in[2];
    const unsigned char* kpm_raw = (const unsigned char*)d_in[3];
    const float* Wq = (const float*)d_in[4];
    const float* bq = (const float*)d_in[5];
    const float* Wk = (const float*)d_in[6];
    const float* bk = (const float*)d_in[7];
    const float* Wv = (const float*)d_in[8];
    const float* bv = (const float*)d_in[9];
    const float* Wo = (const float*)d_in[10];
    const float* bo = (const float*)d_in[11];
    float* out = (float*)d_out;

    char* ws = (char*)d_ws;
    size_t off = 0;
    auto alloc = [&](size_t bytes) {
        char* p = ws + off;
        off += (bytes + 255) & ~(size_t)255;
        return p;
    };
    const size_t SZ_X = (size_t)4096 * 1024 * sizeof(bf16_t);  // 8 MB
    const size_t SZ_W = (size_t)1024 * 1024 * sizeof(bf16_t);  // 2 MB
    bf16_t* xq  = (bf16_t*)alloc(SZ_X);   // xq,xk,xv contiguous (z-indexed)
    bf16_t* xk  = (bf16_t*)alloc(SZ_X);
    bf16_t* xv  = (bf16_t*)alloc(SZ_X);
    bf16_t* wqb = (bf16_t*)alloc(SZ_W);   // wqb..wob contiguous (z-indexed)
    bf16_t* wkb = (bf16_t*)alloc(SZ_W);
    bf16_t* wvb = (bf16_t*)alloc(SZ_W);
    bf16_t* wob = (bf16_t*)alloc(SZ_W);
    bf16_t* qhB = (bf16_t*)alloc(SZ_X);   // qhB,khB,vhB contiguous (z-indexed)
    bf16_t* khB = (bf16_t*)alloc(SZ_X);
    bf16_t* vhB = (bf16_t*)alloc(SZ_X);
    bf16_t* ctxB = (bf16_t*)alloc(SZ_X);
    unsigned long long* mbits = (unsigned long long*)alloc(64 * sizeof(unsigned long long));
    (void)xk; (void)xv; (void)wkb; (void)wvb;

    prep_mask_kernel<<<1, 64, 0, stream>>>(kpm_raw, mbits);
    cvt_x3_kernel<<<6144, 256, 0, stream>>>(query, key_, value, xq);
    cvt_w4_kernel<<<2048, 256, 0, stream>>>(Wq, Wk, Wv, Wo, wqb);

    // QKV projections in one dispatch: grid.z = 3 -> 768 blocks (3/CU)
    gemm_kernel<<<dim3(8, 32, 3), 256, 0, stream>>>(xq, wqb, bq, bk, bv, qhB, nullptr, 0);

    dim3 gattn(32, 32);  // T/64 x B*H
    attn_kernel<<<gattn, 256, 0, stream>>>(qhB, khB, vhB, mbits, ctxB);

    gemm_kernel<<<dim3(8, 32, 1), 256, 0, stream>>>(ctxB, wob, bo, bo, bo, nullptr, out, 1);
}